// Round 2
// baseline (148.495 us; speedup 1.0000x reference)
//
#include <hip/hip_runtime.h>

// FCOS Revision_PRED refinement.
// Outputs (flat float32, in return order):
//   [0, N2*4)              refined_boxes [N2,4]
//   [N2*4, N2*5)           s2            [N2]
//   [N2*5, N2*6)           c2            [N2] (int -> float)
//   [N2*6, N2*6+N1)        missing_mask  [N1] (bool -> 0/1)
//   [N2*6+N1, ...)         ious          [N1,N2]
//
// Algebraic reductions vs the reference:
//  - columns are independent under the iterative suppression; the <=8
//    suppressed entries + final winner are exactly the column's top-9
//    values >0.5 in (value desc, row asc) order.
//  - missing_mask is invariant under suppression (>0.5 -> ==0.5, both
//    fail iou<0.5), so it comes from the original matrix via row ballots.

constexpr int TOPK = 9;  // up to 8 suppressions + final winner

__device__ __forceinline__ void topk_insert(float (&tv)[TOPK], int (&ti)[TOPK],
                                            float v, int r) {
#pragma unroll
    for (int j = TOPK - 1; j >= 0; --j) {
        const bool gt_cur  = v > tv[j];
        const bool gt_prev = (j > 0) ? (v > tv[j - 1]) : false;
        if (gt_cur) {
            if (gt_prev) { tv[j] = tv[j - 1]; ti[j] = ti[j - 1]; }
            else         { tv[j] = v;         ti[j] = r; }
        }
    }
}

// ---------------------------------------------------------------------------
// Kernel A: IoU matrix (float2/thread), per-column partial top-9 + count,
// per-(split,wave) row-any bitmaps. Everything written exactly once -> no
// memset needed. thread = 2 adjacent columns; blockIdx.y = row split.
// n2 assumed even (4096 here).
// ---------------------------------------------------------------------------
__global__ __launch_bounds__(256) void iou_topk_kernel(
    const float* __restrict__ b1, const float* __restrict__ b2,
    float* __restrict__ ious, unsigned char* __restrict__ counts,
    unsigned long long* __restrict__ top,
    unsigned long long* __restrict__ rowflags,
    int n1, int n2, int rows_per_split, int WX, int W64)
{
    const int tid = blockIdx.x * blockDim.x + threadIdx.x;
    const int c0 = tid * 2;
    if (c0 >= n2) return;
    const int s = blockIdx.y;
    const int wx = tid >> 6;                       // global wave-x id (128 cols/wave)
    const bool lane0 = (threadIdx.x & 63u) == 0u;

    const float4 bA = reinterpret_cast<const float4*>(b2)[c0];
    const float4 bB = reinterpret_cast<const float4*>(b2)[c0 + 1];
    const float aA = (bA.z - bA.x) * (bA.w - bA.y);
    const float aB = (bB.z - bB.x) * (bB.w - bB.y);

    float tvA[TOPK], tvB[TOPK];
    int   tiA[TOPK], tiB[TOPK];
#pragma unroll
    for (int j = 0; j < TOPK; ++j) {
        tvA[j] = 0.5f; tvB[j] = 0.5f; tiA[j] = -1; tiB[j] = -1;
    }

    const int r0 = s * rows_per_split;
    const int r1 = min(r0 + rows_per_split, n1);
    unsigned long long rowbits = 0ull;
    float* orow = ious + (size_t)r0 * n2 + c0;

    for (int r = r0; r < r1; ++r, orow += n2) {
        const float4 p = reinterpret_cast<const float4*>(b1)[r];  // wave-uniform
        const float a1 = (p.z - p.x) * (p.w - p.y);

        const float wxA = fmaxf(fminf(p.z, bA.z) - fmaxf(p.x, bA.x), 0.0f);
        const float wyA = fmaxf(fminf(p.w, bA.w) - fmaxf(p.y, bA.y), 0.0f);
        const float ovA = wxA * wyA;
        const float unA = fmaxf(a1 + aA - ovA, 1e-6f);
        float rcA = __builtin_amdgcn_rcpf(unA);
        rcA = rcA * fmaf(-unA, rcA, 2.0f);         // 1 Newton step, ~1 ulp
        const float vA = ovA * rcA;

        const float wxB = fmaxf(fminf(p.z, bB.z) - fmaxf(p.x, bB.x), 0.0f);
        const float wyB = fmaxf(fminf(p.w, bB.w) - fmaxf(p.y, bB.y), 0.0f);
        const float ovB = wxB * wyB;
        const float unB = fmaxf(a1 + aB - ovB, 1e-6f);
        float rcB = __builtin_amdgcn_rcpf(unB);
        rcB = rcB * fmaf(-unB, rcB, 2.0f);
        const float vB = ovB * rcB;

        *reinterpret_cast<float2*>(orow) = make_float2(vA, vB);

        const unsigned long long m = __ballot(fmaxf(vA, vB) >= 0.5f);
        rowbits |= m ? (1ull << ((r - r0) & 63)) : 0ull;
        if (((r - r0) & 63) == 63) {
            if (lane0)
                rowflags[((size_t)s * WX + wx) * W64 + ((r - r0) >> 6)] = rowbits;
            rowbits = 0ull;
        }

        if (vA > tvA[TOPK - 1]) topk_insert(tvA, tiA, vA, r);
        if (vB > tvB[TOPK - 1]) topk_insert(tvB, tiB, vB, r);
    }
    const int nrows = r1 - r0;
    if ((nrows & 63) != 0 && lane0)
        rowflags[((size_t)s * WX + wx) * W64 + ((nrows - 1) >> 6)] = rowbits;

    int cntA = 0, cntB = 0;
#pragma unroll
    for (int j = 0; j < TOPK; ++j) {
        cntA += (tvA[j] > 0.5f) ? 1 : 0;
        cntB += (tvB[j] > 0.5f) ? 1 : 0;
    }
    const size_t cbase = (size_t)s * n2 + c0;
    *reinterpret_cast<unsigned short*>(counts + cbase) =
        (unsigned short)(cntA | (cntB << 8));
    if (cntA) {
        unsigned long long* L = top + cbase * TOPK;
#pragma unroll
        for (int j = 0; j < TOPK; ++j)
            L[j] = ((unsigned long long)__float_as_uint(tvA[j]) << 32)
                 | (unsigned long long)(unsigned int)tiA[j];
    }
    if (cntB) {
        unsigned long long* L = top + (cbase + 1) * TOPK;
#pragma unroll
        for (int j = 0; j < TOPK; ++j)
            L[j] = ((unsigned long long)__float_as_uint(tvB[j]) << 32)
                 | (unsigned long long)(unsigned int)tiB[j];
    }
}

// ---------------------------------------------------------------------------
// Kernel B: merge non-empty partial top-9 lists (row-ascending across splits
// preserves jnp.argmax first-index tie-break), simulate <=8 suppressions,
// scatter the 0.5s, write refined boxes/scores/classes.
// ---------------------------------------------------------------------------
__global__ __launch_bounds__(256) void refine_kernel(
    const float* __restrict__ b1, const float* __restrict__ s1,
    const int* __restrict__ c1,
    const float* __restrict__ b2, const float* __restrict__ s2,
    const int* __restrict__ c2,
    const unsigned char* __restrict__ counts,
    const unsigned long long* __restrict__ top,
    float* __restrict__ out_boxes, float* __restrict__ out_s,
    float* __restrict__ out_c, float* __restrict__ ious,
    int n2, int S)
{
    const int c = blockIdx.x * blockDim.x + threadIdx.x;
    if (c >= n2) return;

    float tv[TOPK];
    int   ti[TOPK];
#pragma unroll
    for (int j = 0; j < TOPK; ++j) { tv[j] = 0.5f; ti[j] = -1; }

    for (int s = 0; s < S; ++s) {
        const int cs = counts[(size_t)s * n2 + c];
        if (cs == 0) continue;
        const unsigned long long* L = top + ((size_t)s * n2 + c) * TOPK;
        for (int e = 0; e < cs; ++e) {
            const unsigned long long pk = L[e];
            const float v = __uint_as_float((unsigned int)(pk >> 32));
            const int r = (int)(unsigned int)(pk & 0xffffffffull);
            topk_insert(tv, ti, v, r);
        }
    }

    int cnt = 0;
#pragma unroll
    for (int j = 0; j < TOPK; ++j) cnt += (tv[j] > 0.5f) ? 1 : 0;

    const float s2c = s2[c];
    float s1v[TOPK];
#pragma unroll
    for (int j = 0; j < TOPK; ++j) s1v[j] = (j < cnt) ? s1[ti[j]] : 0.0f;

    // k = length of maximal prefix with scores1 < scores2 (suppressed), cap 8
    int k = 0;
#pragma unroll
    for (int j = 0; j < 8; ++j)
        if (j < cnt && k == j && s1v[j] < s2c) k = j + 1;

    // scatter the suppressions (entries replaced by exactly 0.5)
#pragma unroll
    for (int j = 0; j < 8; ++j)
        if (j < k) ious[(size_t)ti[j] * n2 + c] = 0.5f;

    const bool refine = (k < cnt);
    int winner = -1; float wscore = 0.0f;
#pragma unroll
    for (int j = 0; j < TOPK; ++j)
        if (j == k) { winner = ti[j]; wscore = s1v[j]; }

    float4 ob; float os, oc;
    if (refine) {
        ob = reinterpret_cast<const float4*>(b1)[winner];
        os = wscore;
        oc = (float)c1[winner];
    } else {
        ob = reinterpret_cast<const float4*>(b2)[c];
        os = s2c;
        oc = (float)c2[c];
    }
    ob.x = fmaxf(ob.x, 0.0f); ob.y = fmaxf(ob.y, 0.0f);   // (b+|b|)*0.5
    ob.z = fmaxf(ob.z, 0.0f); ob.w = fmaxf(ob.w, 0.0f);
    reinterpret_cast<float4*>(out_boxes)[c] = ob;
    out_s[c] = os;
    out_c[c] = oc;
}

// ---------------------------------------------------------------------------
// Kernel C: missing_mask[r] = !any(iou >= 0.5 in row r), from bitmaps.
// ---------------------------------------------------------------------------
__global__ void missing_kernel(const unsigned long long* __restrict__ rowflags,
                               float* __restrict__ out_m,
                               int n1, int WX, int rps, int W64)
{
    const int r = blockIdx.x * blockDim.x + threadIdx.x;
    if (r >= n1) return;
    const int s  = r / rps;
    const int rr = r - s * rps;
    const int w  = rr >> 6, b = rr & 63;
    unsigned long long m = 0ull;
    for (int x = 0; x < WX; ++x)
        m |= rowflags[((size_t)s * WX + x) * W64 + w];
    out_m[r] = ((m >> b) & 1ull) ? 0.0f : 1.0f;
}

extern "C" void kernel_launch(void* const* d_in, const int* in_sizes, int n_in,
                              void* d_out, int out_size, void* d_ws, size_t ws_size,
                              hipStream_t stream) {
    (void)n_in; (void)out_size;
    const float* b1 = (const float*)d_in[0];
    const float* s1 = (const float*)d_in[1];
    const int*   c1 = (const int*)d_in[2];
    const float* b2 = (const float*)d_in[3];
    const float* s2 = (const float*)d_in[4];
    const int*   c2 = (const int*)d_in[5];
    const int n1 = in_sizes[1];   // 8192
    const int n2 = in_sizes[4];   // 4096

    float* out       = (float*)d_out;
    float* out_boxes = out;
    float* out_s     = out + (size_t)n2 * 4;
    float* out_c     = out_s + n2;
    float* out_m     = out_c + n2;
    float* out_ious  = out_m + n1;

    const int WX = (n2 + 127) / 128;           // waves across columns (128 cols/wave)
    int rps = 64;                               // rows per split
    int S   = (n1 + rps - 1) / rps;             // 128 splits
    size_t counts_b, top_off, top_b, flag_off, flag_b;
    for (;;) {
        counts_b = (size_t)S * n2;
        top_off  = (counts_b + 15) & ~(size_t)15;
        top_b    = (size_t)S * n2 * TOPK * sizeof(unsigned long long);
        flag_off = top_off + top_b;
        flag_b   = (size_t)S * WX * (size_t)((rps + 63) >> 6) * 8;
        if (flag_off + flag_b <= ws_size || S == 1) break;
        rps <<= 1; S = (n1 + rps - 1) / rps;    // shrink ws footprint if needed
    }
    const int W64 = (rps + 63) >> 6;
    unsigned char*      counts   = (unsigned char*)d_ws;
    unsigned long long* top      = (unsigned long long*)((char*)d_ws + top_off);
    unsigned long long* rowflags = (unsigned long long*)((char*)d_ws + flag_off);

    dim3 gridA((n2 / 2 + 255) / 256, S);
    iou_topk_kernel<<<gridA, 256, 0, stream>>>(b1, b2, out_ious, counts, top,
                                               rowflags, n1, n2, rps, WX, W64);
    refine_kernel<<<(n2 + 255) / 256, 256, 0, stream>>>(
        b1, s1, c1, b2, s2, c2, counts, top, out_boxes, out_s, out_c,
        out_ious, n2, S);
    missing_kernel<<<(n1 + 255) / 256, 256, 0, stream>>>(rowflags, out_m,
                                                         n1, WX, rps, W64);
}

// Round 3
// 57.965 us; speedup vs baseline: 2.5618x; 2.5618x over previous
//
#include <hip/hip_runtime.h>

// FCOS Revision_PRED refinement.
// Outputs (flat float32, in return order):
//   [0, N2*4)              refined_boxes [N2,4]
//   [N2*4, N2*5)           s2            [N2]
//   [N2*5, N2*6)           c2            [N2] (int -> float)
//   [N2*6, N2*6+N1)        missing_mask  [N1] (bool -> 0/1)
//   [N2*6+N1, ...)         ious          [N1,N2]
//
// Algebraic reductions vs the reference:
//  - columns are independent under the iterative suppression; the <=8
//    suppressed entries + final winner are exactly the column's entries
//    >0.5 in (value desc, row asc) order -> top-9 suffices.
//  - entries >=0.5 are RARE (~tens/column): extract them with atomic
//    appends instead of dense per-split top-k lists (round-2's refine
//    kernel was 131us latency-bound walking 128 dense lists/column).
//  - missing_mask is invariant under suppression (>0.5 -> ==0.5 both fail
//    iou<0.5), so row flags come from the v>=0.5 candidates directly.

constexpr int TOPK = 9;  // up to 8 suppressions + final winner

// ---------------------------------------------------------------------------
// Kernel A: IoU matrix (4 cols/thread, float4 stores, exact IEEE div) +
// rare-candidate append + row flags. blockIdx.y = row split (free knob).
// n2 assumed multiple of 4 (4096 here).
// ---------------------------------------------------------------------------
__global__ __launch_bounds__(256) void iou_cand_kernel(
    const float* __restrict__ b1, const float* __restrict__ b2,
    float* __restrict__ ious,
    unsigned int* __restrict__ cnt, unsigned long long* __restrict__ cand,
    unsigned char* __restrict__ rowflag,
    int n1, int n2, int rps, int cap)
{
    const int tid = blockIdx.x * blockDim.x + threadIdx.x;
    const int c0 = tid * 4;
    if (c0 >= n2) return;
    const int r0 = blockIdx.y * rps;
    const int r1 = min(r0 + rps, n1);

    float4 bx[4]; float ar[4];
#pragma unroll
    for (int k = 0; k < 4; ++k) {
        bx[k] = reinterpret_cast<const float4*>(b2)[c0 + k];
        ar[k] = (bx[k].z - bx[k].x) * (bx[k].w - bx[k].y);
    }

    float* orow = ious + (size_t)r0 * n2 + c0;
    for (int r = r0; r < r1; ++r, orow += n2) {
        const float4 p = reinterpret_cast<const float4*>(b1)[r];  // scalar (uniform)
        const float a1 = (p.z - p.x) * (p.w - p.y);
        float v[4];
#pragma unroll
        for (int k = 0; k < 4; ++k) {
            const float wx = fmaxf(fminf(p.z, bx[k].z) - fmaxf(p.x, bx[k].x), 0.0f);
            const float wy = fmaxf(fminf(p.w, bx[k].w) - fmaxf(p.y, bx[k].y), 0.0f);
            const float ov = wx * wy;
            const float un = fmaxf(a1 + ar[k] - ov, 1e-6f);
            v[k] = ov / un;                      // IEEE div: bit-exact vs numpy
        }
        *reinterpret_cast<float4*>(orow) = make_float4(v[0], v[1], v[2], v[3]);

        if (fmaxf(fmaxf(v[0], v[1]), fmaxf(v[2], v[3])) >= 0.5f) {  // rare
            rowflag[r] = 1;
#pragma unroll
            for (int k = 0; k < 4; ++k) {
                if (v[k] >= 0.5f) {
                    const unsigned int idx = atomicAdd(&cnt[c0 + k], 1u);
                    if (idx < (unsigned int)cap)
                        // pack (value desc, row asc) into one u64 key:
                        // equal values -> larger ~r (smaller r) wins.
                        cand[(size_t)(c0 + k) * cap + idx] =
                            ((unsigned long long)__float_as_uint(v[k]) << 32)
                          | (unsigned long long)(~(unsigned int)r);
                }
            }
        }
    }
}

// ---------------------------------------------------------------------------
// Kernel B: per column, top-9 from the candidate list (u64 keys make the
// result independent of append order), simulate <=8 suppressions, scatter
// the 0.5s, write refined boxes/scores/classes.
// ---------------------------------------------------------------------------
__global__ __launch_bounds__(256) void refine_kernel(
    const float* __restrict__ b1, const float* __restrict__ s1,
    const int* __restrict__ c1,
    const float* __restrict__ b2, const float* __restrict__ s2,
    const int* __restrict__ c2,
    const unsigned int* __restrict__ cnt,
    const unsigned long long* __restrict__ cand,
    float* __restrict__ out_boxes, float* __restrict__ out_s,
    float* __restrict__ out_c, float* __restrict__ ious,
    int n2, int cap)
{
    const int c = blockIdx.x * blockDim.x + threadIdx.x;
    if (c >= n2) return;

    unsigned long long t[TOPK];
#pragma unroll
    for (int j = 0; j < TOPK; ++j) t[j] = 0ull;   // 0 < any valid key

    const int n = min((int)cnt[c], cap);
    const unsigned long long* L = cand + (size_t)c * cap;
    for (int e = 0; e < n; ++e) {
        const unsigned long long pk = L[e];
        const float v = __uint_as_float((unsigned int)(pk >> 32));
        if (!(v > 0.5f)) continue;     // v==0.5 exactly: row-flag only
        if (pk > t[TOPK - 1]) {
#pragma unroll
            for (int j = TOPK - 1; j >= 0; --j) {
                const bool gt_cur  = pk > t[j];
                const bool gt_prev = (j > 0) ? (pk > t[j - 1]) : false;
                if (gt_cur) t[j] = gt_prev ? t[j - 1] : pk;
            }
        }
    }

    int m = 0;
#pragma unroll
    for (int j = 0; j < TOPK; ++j) m += (t[j] != 0ull) ? 1 : 0;

    int   ti[TOPK];
    float s1v[TOPK];
    const float s2c = s2[c];
#pragma unroll
    for (int j = 0; j < TOPK; ++j) {
        ti[j]  = (int)~(unsigned int)(t[j] & 0xffffffffull);
        s1v[j] = (j < m) ? s1[ti[j]] : 0.0f;
    }

    // k = length of maximal prefix with scores1 < scores2 (suppressed), cap 8
    int k = 0;
#pragma unroll
    for (int j = 0; j < 8; ++j)
        if (j < m && k == j && s1v[j] < s2c) k = j + 1;

    // scatter the suppressions (entries replaced by exactly 0.5)
#pragma unroll
    for (int j = 0; j < 8; ++j)
        if (j < k) ious[(size_t)ti[j] * n2 + c] = 0.5f;

    const bool refine = (k < m);
    int winner = 0; float wsc = 0.0f;
#pragma unroll
    for (int j = 0; j < TOPK; ++j)
        if (j == k) { winner = ti[j]; wsc = s1v[j]; }

    float4 ob; float os, oc;
    if (refine) {
        ob = reinterpret_cast<const float4*>(b1)[winner];
        os = wsc;
        oc = (float)c1[winner];
    } else {
        ob = reinterpret_cast<const float4*>(b2)[c];
        os = s2c;
        oc = (float)c2[c];
    }
    ob.x = fmaxf(ob.x, 0.0f); ob.y = fmaxf(ob.y, 0.0f);   // (b+|b|)*0.5
    ob.z = fmaxf(ob.z, 0.0f); ob.w = fmaxf(ob.w, 0.0f);
    reinterpret_cast<float4*>(out_boxes)[c] = ob;
    out_s[c] = os;
    out_c[c] = oc;
}

// ---------------------------------------------------------------------------
// Kernel C: missing_mask[r] = !any(iou >= 0.5 in row r)
// ---------------------------------------------------------------------------
__global__ void missing_kernel(const unsigned char* __restrict__ rowflag,
                               float* __restrict__ out_m, int n1)
{
    const int r = blockIdx.x * blockDim.x + threadIdx.x;
    if (r < n1) out_m[r] = rowflag[r] ? 0.0f : 1.0f;
}

extern "C" void kernel_launch(void* const* d_in, const int* in_sizes, int n_in,
                              void* d_out, int out_size, void* d_ws, size_t ws_size,
                              hipStream_t stream) {
    (void)n_in; (void)out_size;
    const float* b1 = (const float*)d_in[0];
    const float* s1 = (const float*)d_in[1];
    const int*   c1 = (const int*)d_in[2];
    const float* b2 = (const float*)d_in[3];
    const float* s2 = (const float*)d_in[4];
    const int*   c2 = (const int*)d_in[5];
    const int n1 = in_sizes[1];   // 8192
    const int n2 = in_sizes[4];   // 4096

    float* out       = (float*)d_out;
    float* out_boxes = out;
    float* out_s     = out + (size_t)n2 * 4;
    float* out_c     = out_s + n2;
    float* out_m     = out_c + n2;
    float* out_ious  = out_m + n1;

    // ws: [cnt: n2 u32][rowflag: n1 u8][cand: n2*cap u64]
    const size_t cnt_b    = (size_t)n2 * sizeof(unsigned int);
    const size_t flag_b   = (size_t)n1;
    const size_t cand_off = (cnt_b + flag_b + 15) & ~(size_t)15;
    int cap = n1;                                  // can never overflow at n1
    while (cap > 64 && cand_off + (size_t)n2 * cap * 8 > ws_size) cap >>= 1;
    unsigned int*       cnt     = (unsigned int*)d_ws;
    unsigned char*      rowflag = (unsigned char*)d_ws + cnt_b;
    unsigned long long* cand    = (unsigned long long*)((char*)d_ws + cand_off);

    hipMemsetAsync(d_ws, 0, cnt_b + flag_b, stream);

    const int bx = (n2 / 4 + 255) / 256;           // 4 blocks at n2=4096
    int S = 1024 / bx; if (S < 1) S = 1; if (S > n1) S = n1;
    const int rps = (n1 + S - 1) / S;              // 32 rows/block at defaults

    dim3 gridA(bx, S);
    iou_cand_kernel<<<gridA, 256, 0, stream>>>(b1, b2, out_ious, cnt, cand,
                                               rowflag, n1, n2, rps, cap);
    refine_kernel<<<(n2 + 255) / 256, 256, 0, stream>>>(
        b1, s1, c1, b2, s2, c2, cnt, cand, out_boxes, out_s, out_c,
        out_ious, n2, cap);
    missing_kernel<<<(n1 + 255) / 256, 256, 0, stream>>>(rowflag, out_m, n1);
}

// Round 4
// 55.357 us; speedup vs baseline: 2.6825x; 1.0471x over previous
//
#include <hip/hip_runtime.h>

// FCOS Revision_PRED refinement.
// Outputs (flat float32, in return order):
//   [0, N2*4)              refined_boxes [N2,4]
//   [N2*4, N2*5)           s2            [N2]
//   [N2*5, N2*6)           c2            [N2] (int -> float)
//   [N2*6, N2*6+N1)        missing_mask  [N1] (bool -> 0/1)
//   [N2*6+N1, ...)         ious          [N1,N2]
//
// Algebraic reductions vs the reference:
//  - columns are independent under the iterative suppression; the <=8
//    suppressed entries + final winner are exactly the column's entries
//    >0.5 in (value desc, row asc) order -> per-column top-9 suffices.
//  - entries >0.5 are rare: extract via atomic append (e-major layout so
//    the merge kernel reads them coalesced), not dense per-split lists.
//  - missing_mask is invariant under suppression (>0.5 -> ==0.5 both fail
//    iou<0.5): row flags come from the v>=0.5 hits directly.
//  - all IoU arithmetic uses __f*_rn intrinsics to block FMA contraction:
//    bit-matches numpy's separately-rounded ops (round-3 absmax 2^-10 came
//    from a contracted a1+a2-wx*wy flipping a near-tied selection).

constexpr int TOPK = 9;  // up to 8 suppressions + final winner

__device__ __forceinline__ void key_insert(unsigned long long (&t)[TOPK],
                                           unsigned long long pk) {
    if (pk > t[TOPK - 1]) {
#pragma unroll
        for (int j = TOPK - 1; j >= 0; --j) {
            const bool gt_cur  = pk > t[j];
            const bool gt_prev = (j > 0) ? (pk > t[j - 1]) : false;
            if (gt_cur) t[j] = gt_prev ? t[j - 1] : pk;
        }
    }
}

// ---------------------------------------------------------------------------
// Kernel A: IoU matrix (4 cols/thread, float4 stores, contraction-safe) +
// rare candidate append (e-major) + row flags. blockIdx.y = row split.
// n2 assumed multiple of 4 (4096 here).
// ---------------------------------------------------------------------------
__global__ __launch_bounds__(256) void iou_cand_kernel(
    const float* __restrict__ b1, const float* __restrict__ b2,
    float* __restrict__ ious,
    unsigned int* __restrict__ cnt, unsigned long long* __restrict__ cand,
    unsigned char* __restrict__ rowflag,
    int n1, int n2, int rps, int cap)
{
    const int tid = blockIdx.x * blockDim.x + threadIdx.x;
    const int c0 = tid * 4;
    if (c0 >= n2) return;
    const int r0 = blockIdx.y * rps;
    const int r1 = min(r0 + rps, n1);

    float4 bx[4]; float ar[4];
#pragma unroll
    for (int k = 0; k < 4; ++k) {
        bx[k] = reinterpret_cast<const float4*>(b2)[c0 + k];
        ar[k] = __fmul_rn(__fsub_rn(bx[k].z, bx[k].x),
                          __fsub_rn(bx[k].w, bx[k].y));
    }

    float* orow = ious + (size_t)r0 * n2 + c0;
    for (int r = r0; r < r1; ++r, orow += n2) {
        const float4 p = reinterpret_cast<const float4*>(b1)[r];  // wave-uniform
        const float a1 = __fmul_rn(__fsub_rn(p.z, p.x), __fsub_rn(p.w, p.y));
        float v[4];
#pragma unroll
        for (int k = 0; k < 4; ++k) {
            const float wx = fmaxf(__fsub_rn(fminf(p.z, bx[k].z),
                                             fmaxf(p.x, bx[k].x)), 0.0f);
            const float wy = fmaxf(__fsub_rn(fminf(p.w, bx[k].w),
                                             fmaxf(p.y, bx[k].y)), 0.0f);
            const float ov = __fmul_rn(wx, wy);
            const float un = fmaxf(__fsub_rn(__fadd_rn(a1, ar[k]), ov), 1e-6f);
            v[k] = __fdiv_rn(ov, un);            // bit-exact vs numpy
        }
        *reinterpret_cast<float4*>(orow) = make_float4(v[0], v[1], v[2], v[3]);

        if (fmaxf(fmaxf(v[0], v[1]), fmaxf(v[2], v[3])) >= 0.5f) {  // rare
            rowflag[r] = 1;
#pragma unroll
            for (int k = 0; k < 4; ++k) {
                if (v[k] > 0.5f) {
                    const unsigned int idx = atomicAdd(&cnt[c0 + k], 1u);
                    if (idx < (unsigned int)cap)
                        // key packs (value desc, row asc): ties -> smaller r
                        // (larger ~r) wins, matching jnp.argmax.
                        cand[(size_t)idx * n2 + (c0 + k)] =
                            ((unsigned long long)__float_as_uint(v[k]) << 32)
                          | (unsigned long long)(~(unsigned int)r);
                }
            }
        }
    }
}

// ---------------------------------------------------------------------------
// Kernel B (fused refine + missing): per column, top-9 from the candidate
// list (u64 keys -> append-order independent), simulate <=8 suppressions,
// scatter the 0.5s, write boxes/scores/classes; threads >= n2 handle rows'
// missing_mask. Overflowed columns (cnt > cap) rescan their ious column.
// ---------------------------------------------------------------------------
__global__ __launch_bounds__(64) void refine_missing_kernel(
    const float* __restrict__ b1, const float* __restrict__ s1,
    const int* __restrict__ c1,
    const float* __restrict__ b2, const float* __restrict__ s2,
    const int* __restrict__ c2,
    const unsigned int* __restrict__ cnt,
    const unsigned long long* __restrict__ cand,
    const unsigned char* __restrict__ rowflag,
    float* __restrict__ out_boxes, float* __restrict__ out_s,
    float* __restrict__ out_c, float* __restrict__ out_m,
    float* __restrict__ ious,
    int n1, int n2, int cap)
{
    const int tid = blockIdx.x * blockDim.x + threadIdx.x;

    if (tid < n1)                                   // missing_mask part
        out_m[tid] = rowflag[tid] ? 0.0f : 1.0f;

    const int c = tid;
    if (c >= n2) return;

    unsigned long long t[TOPK];
#pragma unroll
    for (int j = 0; j < TOPK; ++j) t[j] = 0ull;     // 0 < any valid key

    const int n = (int)cnt[c];
    if (n <= cap) {
        const unsigned long long* L = cand + c;     // e-major: coalesced
        for (int e = 0; e < n; ++e)
            key_insert(t, L[(size_t)e * n2]);
    } else {                                        // overflow: rescan column
        for (int r = 0; r < n1; ++r) {
            const float v = ious[(size_t)r * n2 + c];
            if (v > 0.5f)
                key_insert(t, ((unsigned long long)__float_as_uint(v) << 32)
                            | (unsigned long long)(~(unsigned int)r));
        }
    }

    int m = 0;
#pragma unroll
    for (int j = 0; j < TOPK; ++j) m += (t[j] != 0ull) ? 1 : 0;

    int   ti[TOPK];
    float s1v[TOPK];
    const float s2c = s2[c];
#pragma unroll
    for (int j = 0; j < TOPK; ++j) {
        ti[j]  = (int)~(unsigned int)(t[j] & 0xffffffffull);
        s1v[j] = (j < m) ? s1[ti[j]] : 0.0f;
    }

    // k = length of maximal prefix with scores1 < scores2 (suppressed), cap 8
    int k = 0;
#pragma unroll
    for (int j = 0; j < 8; ++j)
        if (j < m && k == j && s1v[j] < s2c) k = j + 1;

    // scatter the suppressions (entries replaced by exactly 0.5)
#pragma unroll
    for (int j = 0; j < 8; ++j)
        if (j < k) ious[(size_t)ti[j] * n2 + c] = 0.5f;

    const bool refine = (k < m);
    int winner = 0; float wsc = 0.0f;
#pragma unroll
    for (int j = 0; j < TOPK; ++j)
        if (j == k) { winner = ti[j]; wsc = s1v[j]; }

    float4 ob; float os, oc;
    if (refine) {
        ob = reinterpret_cast<const float4*>(b1)[winner];
        os = wsc;
        oc = (float)c1[winner];
    } else {
        ob = reinterpret_cast<const float4*>(b2)[c];
        os = s2c;
        oc = (float)c2[c];
    }
    ob.x = fmaxf(ob.x, 0.0f); ob.y = fmaxf(ob.y, 0.0f);   // (b+|b|)*0.5
    ob.z = fmaxf(ob.z, 0.0f); ob.w = fmaxf(ob.w, 0.0f);
    reinterpret_cast<float4*>(out_boxes)[c] = ob;
    out_s[c] = os;
    out_c[c] = oc;
}

extern "C" void kernel_launch(void* const* d_in, const int* in_sizes, int n_in,
                              void* d_out, int out_size, void* d_ws, size_t ws_size,
                              hipStream_t stream) {
    (void)n_in; (void)out_size;
    const float* b1 = (const float*)d_in[0];
    const float* s1 = (const float*)d_in[1];
    const int*   c1 = (const int*)d_in[2];
    const float* b2 = (const float*)d_in[3];
    const float* s2 = (const float*)d_in[4];
    const int*   c2 = (const int*)d_in[5];
    const int n1 = in_sizes[1];   // 8192
    const int n2 = in_sizes[4];   // 4096

    float* out       = (float*)d_out;
    float* out_boxes = out;
    float* out_s     = out + (size_t)n2 * 4;
    float* out_c     = out_s + n2;
    float* out_m     = out_c + n2;
    float* out_ious  = out_m + n1;

    // ws: [cnt: n2 u32][rowflag: n1 u8][cand: cap*n2 u64, e-major]
    const size_t cnt_b    = (size_t)n2 * sizeof(unsigned int);
    const size_t flag_b   = (size_t)n1;
    const size_t cand_off = (cnt_b + flag_b + 15) & ~(size_t)15;
    int cap = 1024;                                // overflow path covers rest
    while (cap > 16 && cand_off + (size_t)cap * n2 * 8 > ws_size) cap >>= 1;
    unsigned int*       cnt     = (unsigned int*)d_ws;
    unsigned char*      rowflag = (unsigned char*)d_ws + cnt_b;
    unsigned long long* cand    = (unsigned long long*)((char*)d_ws + cand_off);

    hipMemsetAsync(d_ws, 0, cnt_b + flag_b, stream);

    const int bx = (n2 / 4 + 255) / 256;           // 4 at n2=4096
    int S = 2048 / bx; if (S < 1) S = 1; if (S > n1) S = n1;   // 512 splits
    const int rps = (n1 + S - 1) / S;              // 16 rows/block

    dim3 gridA(bx, S);
    iou_cand_kernel<<<gridA, 256, 0, stream>>>(b1, b2, out_ious, cnt, cand,
                                               rowflag, n1, n2, rps, cap);
    const int ntot = max(n1, n2);
    refine_missing_kernel<<<(ntot + 63) / 64, 64, 0, stream>>>(
        b1, s1, c1, b2, s2, c2, cnt, cand, rowflag,
        out_boxes, out_s, out_c, out_m, out_ious, n1, n2, cap);
}

// Round 5
// 50.895 us; speedup vs baseline: 2.9177x; 1.0877x over previous
//
#include <hip/hip_runtime.h>

// FCOS Revision_PRED refinement.
// Outputs (flat float32, in return order):
//   [0, N2*4)              refined_boxes [N2,4]
//   [N2*4, N2*5)           s2            [N2]
//   [N2*5, N2*6)           c2            [N2] (int -> float)
//   [N2*6, N2*6+N1)        missing_mask  [N1] (bool -> 0/1)
//   [N2*6+N1, ...)         ious          [N1,N2]
//
// Algebraic reductions vs the reference:
//  - columns are independent under the iterative suppression; the <=8
//    suppressed entries + final winner are exactly the column's entries
//    >0.5 in (value desc, row asc) order -> per-column top-9 suffices.
//  - entries >0.5 are rare: extract via atomic append (e-major layout so
//    the merge kernel reads them coalesced), not dense per-split lists.
//  - missing_mask is invariant under suppression (>0.5 -> ==0.5 both fail
//    iou<0.5): row flags come from the v>=0.5 hits directly.
// Numerics:
//  - IEEE f32 div (v_div_scale/.../v_div_fixup, ~20+cyc) made kernel A
//    division-bound (round 4 ~2x over its store floor). Bulk now uses
//    v_rcp + 1 Newton step (<=2ulp); any value > 0.499999 is recomputed
//    with __fdiv_rn so every entry near/above the 0.5 threshold -- i.e.
//    everything that participates in selection -- is bit-exact vs numpy.
//    un is built with __f*_rn to block FMA contraction (must match np's
//    separately-rounded (a1+a2)-ov).

constexpr int TOPK = 9;  // up to 8 suppressions + final winner

__device__ __forceinline__ void key_insert(unsigned long long (&t)[TOPK],
                                           unsigned long long pk) {
    if (pk > t[TOPK - 1]) {
#pragma unroll
        for (int j = TOPK - 1; j >= 0; --j) {
            const bool gt_cur  = pk > t[j];
            const bool gt_prev = (j > 0) ? (pk > t[j - 1]) : false;
            if (gt_cur) t[j] = gt_prev ? t[j - 1] : pk;
        }
    }
}

// ---------------------------------------------------------------------------
// Kernel A: IoU matrix (4 cols/thread, float4 stores) + rare candidate
// append (e-major) + row flags. blockIdx.y = row split.
// n2 assumed multiple of 4 (4096 here).
// ---------------------------------------------------------------------------
__global__ __launch_bounds__(256) void iou_cand_kernel(
    const float* __restrict__ b1, const float* __restrict__ b2,
    float* __restrict__ ious,
    unsigned int* __restrict__ cnt, unsigned long long* __restrict__ cand,
    unsigned char* __restrict__ rowflag,
    int n1, int n2, int rps, int cap)
{
    const int tid = blockIdx.x * blockDim.x + threadIdx.x;
    const int c0 = tid * 4;
    if (c0 >= n2) return;
    const int r0 = blockIdx.y * rps;
    const int r1 = min(r0 + rps, n1);

    float4 bx[4]; float ar[4];
#pragma unroll
    for (int k = 0; k < 4; ++k) {
        bx[k] = reinterpret_cast<const float4*>(b2)[c0 + k];
        ar[k] = __fmul_rn(__fsub_rn(bx[k].z, bx[k].x),
                          __fsub_rn(bx[k].w, bx[k].y));
    }

    float* orow = ious + (size_t)r0 * n2 + c0;
    for (int r = r0; r < r1; ++r, orow += n2) {
        const float4 p = reinterpret_cast<const float4*>(b1)[r];  // wave-uniform
        const float a1 = __fmul_rn(__fsub_rn(p.z, p.x), __fsub_rn(p.w, p.y));
        float v[4], ovs[4], uns[4];
#pragma unroll
        for (int k = 0; k < 4; ++k) {
            const float wx = fmaxf(__fsub_rn(fminf(p.z, bx[k].z),
                                             fmaxf(p.x, bx[k].x)), 0.0f);
            const float wy = fmaxf(__fsub_rn(fminf(p.w, bx[k].w),
                                             fmaxf(p.y, bx[k].y)), 0.0f);
            const float ov = __fmul_rn(wx, wy);
            const float un = fmaxf(__fsub_rn(__fadd_rn(a1, ar[k]), ov), 1e-6f);
            ovs[k] = ov; uns[k] = un;
            float rc = __builtin_amdgcn_rcpf(un);
            rc = rc * fmaf(-un, rc, 2.0f);        // 1 Newton step, <=2 ulp
            v[k] = ov * rc;
        }

        // near-threshold lanes: make bit-exact, flag rows, append candidates.
        // 0.499999 is ~17 ulps below 0.5 -- covers the <=2ulp NR error band.
        const float vmax = fmaxf(fmaxf(v[0], v[1]), fmaxf(v[2], v[3]));
        if (vmax > 0.499999f) {                    // rare wave branch
#pragma unroll
            for (int k = 0; k < 4; ++k) {
                if (v[k] > 0.499999f) {
                    const float ve = __fdiv_rn(ovs[k], uns[k]);  // exact vs np
                    v[k] = ve;
                    if (ve >= 0.5f) {
                        rowflag[r] = 1;
                        if (ve > 0.5f) {
                            const unsigned int idx = atomicAdd(&cnt[c0 + k], 1u);
                            if (idx < (unsigned int)cap)
                                // key packs (value desc, row asc): ties ->
                                // smaller r (larger ~r) wins, as jnp.argmax.
                                cand[(size_t)idx * n2 + (c0 + k)] =
                                    ((unsigned long long)__float_as_uint(ve) << 32)
                                  | (unsigned long long)(~(unsigned int)r);
                        }
                    }
                }
            }
        }
        *reinterpret_cast<float4*>(orow) = make_float4(v[0], v[1], v[2], v[3]);
    }
}

// ---------------------------------------------------------------------------
// Kernel B (fused refine + missing): per column, top-9 from the candidate
// list (u64 keys -> append-order independent), simulate <=8 suppressions,
// scatter the 0.5s, write boxes/scores/classes; threads >= n2 handle rows'
// missing_mask. Overflowed columns (cnt > cap) rescan their ious column.
// ---------------------------------------------------------------------------
__global__ __launch_bounds__(64) void refine_missing_kernel(
    const float* __restrict__ b1, const float* __restrict__ s1,
    const int* __restrict__ c1,
    const float* __restrict__ b2, const float* __restrict__ s2,
    const int* __restrict__ c2,
    const unsigned int* __restrict__ cnt,
    const unsigned long long* __restrict__ cand,
    const unsigned char* __restrict__ rowflag,
    float* __restrict__ out_boxes, float* __restrict__ out_s,
    float* __restrict__ out_c, float* __restrict__ out_m,
    float* __restrict__ ious,
    int n1, int n2, int cap)
{
    const int tid = blockIdx.x * blockDim.x + threadIdx.x;

    if (tid < n1)                                   // missing_mask part
        out_m[tid] = rowflag[tid] ? 0.0f : 1.0f;

    const int c = tid;
    if (c >= n2) return;

    unsigned long long t[TOPK];
#pragma unroll
    for (int j = 0; j < TOPK; ++j) t[j] = 0ull;     // 0 < any valid key

    const int n = (int)cnt[c];
    if (n <= cap) {
        const unsigned long long* L = cand + c;     // e-major: coalesced
        for (int e = 0; e < n; ++e)
            key_insert(t, L[(size_t)e * n2]);
    } else {                                        // overflow: rescan column
        for (int r = 0; r < n1; ++r) {
            const float v = ious[(size_t)r * n2 + c];
            if (v > 0.5f)
                key_insert(t, ((unsigned long long)__float_as_uint(v) << 32)
                            | (unsigned long long)(~(unsigned int)r));
        }
    }

    int m = 0;
#pragma unroll
    for (int j = 0; j < TOPK; ++j) m += (t[j] != 0ull) ? 1 : 0;

    int   ti[TOPK];
    float s1v[TOPK];
    const float s2c = s2[c];
#pragma unroll
    for (int j = 0; j < TOPK; ++j) {
        ti[j]  = (int)~(unsigned int)(t[j] & 0xffffffffull);
        s1v[j] = (j < m) ? s1[ti[j]] : 0.0f;
    }

    // k = length of maximal prefix with scores1 < scores2 (suppressed), cap 8
    int k = 0;
#pragma unroll
    for (int j = 0; j < 8; ++j)
        if (j < m && k == j && s1v[j] < s2c) k = j + 1;

    // scatter the suppressions (entries replaced by exactly 0.5)
#pragma unroll
    for (int j = 0; j < 8; ++j)
        if (j < k) ious[(size_t)ti[j] * n2 + c] = 0.5f;

    const bool refine = (k < m);
    int winner = 0; float wsc = 0.0f;
#pragma unroll
    for (int j = 0; j < TOPK; ++j)
        if (j == k) { winner = ti[j]; wsc = s1v[j]; }

    float4 ob; float os, oc;
    if (refine) {
        ob = reinterpret_cast<const float4*>(b1)[winner];
        os = wsc;
        oc = (float)c1[winner];
    } else {
        ob = reinterpret_cast<const float4*>(b2)[c];
        os = s2c;
        oc = (float)c2[c];
    }
    ob.x = fmaxf(ob.x, 0.0f); ob.y = fmaxf(ob.y, 0.0f);   // (b+|b|)*0.5
    ob.z = fmaxf(ob.z, 0.0f); ob.w = fmaxf(ob.w, 0.0f);
    reinterpret_cast<float4*>(out_boxes)[c] = ob;
    out_s[c] = os;
    out_c[c] = oc;
}

extern "C" void kernel_launch(void* const* d_in, const int* in_sizes, int n_in,
                              void* d_out, int out_size, void* d_ws, size_t ws_size,
                              hipStream_t stream) {
    (void)n_in; (void)out_size;
    const float* b1 = (const float*)d_in[0];
    const float* s1 = (const float*)d_in[1];
    const int*   c1 = (const int*)d_in[2];
    const float* b2 = (const float*)d_in[3];
    const float* s2 = (const float*)d_in[4];
    const int*   c2 = (const int*)d_in[5];
    const int n1 = in_sizes[1];   // 8192
    const int n2 = in_sizes[4];   // 4096

    float* out       = (float*)d_out;
    float* out_boxes = out;
    float* out_s     = out + (size_t)n2 * 4;
    float* out_c     = out_s + n2;
    float* out_m     = out_c + n2;
    float* out_ious  = out_m + n1;

    // ws: [cnt: n2 u32][rowflag: n1 u8][cand: cap*n2 u64, e-major]
    const size_t cnt_b    = (size_t)n2 * sizeof(unsigned int);
    const size_t flag_b   = (size_t)n1;
    const size_t cand_off = (cnt_b + flag_b + 15) & ~(size_t)15;
    int cap = 1024;                                // overflow path covers rest
    while (cap > 16 && cand_off + (size_t)cap * n2 * 8 > ws_size) cap >>= 1;
    unsigned int*       cnt     = (unsigned int*)d_ws;
    unsigned char*      rowflag = (unsigned char*)d_ws + cnt_b;
    unsigned long long* cand    = (unsigned long long*)((char*)d_ws + cand_off);

    hipMemsetAsync(d_ws, 0, cnt_b + flag_b, stream);

    const int bx = (n2 / 4 + 255) / 256;           // 4 at n2=4096
    int S = 2048 / bx; if (S < 1) S = 1; if (S > n1) S = n1;   // 512 splits
    const int rps = (n1 + S - 1) / S;              // 16 rows/block

    dim3 gridA(bx, S);
    iou_cand_kernel<<<gridA, 256, 0, stream>>>(b1, b2, out_ious, cnt, cand,
                                               rowflag, n1, n2, rps, cap);
    const int ntot = max(n1, n2);
    refine_missing_kernel<<<(ntot + 63) / 64, 64, 0, stream>>>(
        b1, s1, c1, b2, s2, c2, cnt, cand, rowflag,
        out_boxes, out_s, out_c, out_m, out_ious, n1, n2, cap);
}